// Round 1
// baseline (118.766 us; speedup 1.0000x reference)
//
#include <hip/hip_runtime.h>

#define G      4      // images per block
#define NCLS   10
#define NPATCH 196
#define FEATN  3920

__global__ __launch_bounds__(256, 2)
void quanv_fused(const float* __restrict__ x,      // (B, 784)
                 const float* __restrict__ fc_w,   // (10, 3920)
                 const float* __restrict__ fc_b,   // (10,)
                 float* __restrict__ out)          // (B, 10)
{
    const int tid  = threadIdx.x;
    const int img0 = blockIdx.x * G;
    const bool active = tid < NPATCH;
    const int pi = tid / 14;
    const int pj = tid - pi * 14;

    float feat[G][20];
    #pragma unroll
    for (int g = 0; g < G; ++g)
        #pragma unroll
        for (int k = 0; k < 20; ++k) feat[g][k] = 0.f;

    if (active) {
        #pragma unroll
        for (int g = 0; g < G; ++g) {
            const float* img = x + (size_t)(img0 + g) * 784;
            // patch pixels: p0=img[2i,2j] p1=img[2i,2j+1] p2=img[2i+1,2j] p3=img[2i+1,2j+1]
            const float2 top = *reinterpret_cast<const float2*>(img + (2 * pi) * 28 + 2 * pj);
            const float2 bot = *reinterpret_cast<const float2*>(img + (2 * pi + 1) * 28 + 2 * pj);
            float s0, c0, s1, c1, s2, c2, s3, c3;
            __sincosf(0.5f * top.x, &s0, &c0);
            __sincosf(0.5f * top.y, &s1, &c1);
            __sincosf(0.5f * bot.x, &s2, &c2);
            __sincosf(0.5f * bot.y, &s3, &c3);
            // amplitude grid a[q0][q1] = RY(p0)|0> ⊗ RY(p1)|0>
            float a00 = c0 * c1, a01 = c0 * s1, a10 = s0 * c1, a11 = s0 * s1;
            #pragma unroll
            for (int r = 0; r < 8; ++r) {
                // CX(0,1): row1 column-swap
                const float b10 = a11, b11 = a10;
                // RY(p0) on q0: rows mixed by [[c0,-s0],[s0,c0]]
                const float n00 = c0 * a00 - s0 * b10;
                const float n01 = c0 * a01 - s0 * b11;
                const float n10 = s0 * a00 + c0 * b10;
                const float n11 = s0 * a01 + c0 * b11;
                a00 = n00; a01 = n01; a10 = n10; a11 = n11;
            }
            const float P[4]  = {a00 * a00, a01 * a01, a10 * a10, a11 * a11}; // [q0*2+q1]
            const float t2[2] = {c2 * c2, s2 * s2};   // [P(q2=0), P(q2=1)]
            const float t3[2] = {c3 * c3, s3 * s3};
            #pragma unroll
            for (int q = 0; q < 4; ++q) {
                // idx = q0*8 + q1*4 + q2*2 + q3
                feat[g][q * 4 + 0] = P[q] * t2[0] * t3[0];
                feat[g][q * 4 + 1] = P[q] * t2[0] * t3[1];
                feat[g][q * 4 + 2] = P[q] * t2[1] * t3[0];
                feat[g][q * 4 + 3] = P[q] * t2[1] * t3[1];
            }
            // sampler: tl = p0, br = p3
            const float sa = s0 * s0, sb = s3 * s3;
            feat[g][16] = (1.f - sa) * (1.f - sb);
            feat[g][17] = (1.f - sa) * sb;
            feat[g][18] = sa * (1.f - sb);
            feat[g][19] = sa * sb;
        }
    }

    float acc[G][NCLS];
    #pragma unroll
    for (int g = 0; g < G; ++g)
        #pragma unroll
        for (int c = 0; c < NCLS; ++c) acc[g][c] = 0.f;

    if (active) {
        #pragma unroll
        for (int c = 0; c < NCLS; ++c) {
            const float* wr = fc_w + c * FEATN;
            const float4* wf = reinterpret_cast<const float4*>(wr + 16 * tid);
            const float4 w0 = wf[0], w1 = wf[1], w2 = wf[2], w3 = wf[3];
            const float4 ws = *reinterpret_cast<const float4*>(wr + 3136 + 4 * tid);
            #pragma unroll
            for (int g = 0; g < G; ++g) {
                float s = feat[g][0] * w0.x + feat[g][1] * w0.y + feat[g][2] * w0.z + feat[g][3] * w0.w;
                s += feat[g][4]  * w1.x + feat[g][5]  * w1.y + feat[g][6]  * w1.z + feat[g][7]  * w1.w;
                s += feat[g][8]  * w2.x + feat[g][9]  * w2.y + feat[g][10] * w2.z + feat[g][11] * w2.w;
                s += feat[g][12] * w3.x + feat[g][13] * w3.y + feat[g][14] * w3.z + feat[g][15] * w3.w;
                s += feat[g][16] * ws.x + feat[g][17] * ws.y + feat[g][18] * ws.z + feat[g][19] * ws.w;
                acc[g][c] = s;
            }
        }
    }

    // 64-lane butterfly reduce each (g,c)
    #pragma unroll
    for (int g = 0; g < G; ++g)
        #pragma unroll
        for (int c = 0; c < NCLS; ++c) {
            float v = acc[g][c];
            #pragma unroll
            for (int off = 32; off > 0; off >>= 1)
                v += __shfl_xor(v, off, 64);
            acc[g][c] = v;
        }

    __shared__ float red[4][G * NCLS];
    __shared__ float lgts[G][NCLS];
    const int wave = tid >> 6;
    const int lane = tid & 63;
    if (lane == 0) {
        #pragma unroll
        for (int g = 0; g < G; ++g)
            #pragma unroll
            for (int c = 0; c < NCLS; ++c)
                red[wave][g * NCLS + c] = acc[g][c];
    }
    __syncthreads();
    if (tid < G * NCLS) {
        const int g = tid / NCLS, c = tid - g * NCLS;
        lgts[g][c] = red[0][tid] + red[1][tid] + red[2][tid] + red[3][tid] + fc_b[c];
    }
    __syncthreads();
    if (tid < G * NCLS) {
        const int g = tid / NCLS, c = tid - g * NCLS;
        float m = -1e30f;
        #pragma unroll
        for (int k = 0; k < NCLS; ++k) m = fmaxf(m, lgts[g][k]);
        float ssum = 0.f;
        #pragma unroll
        for (int k = 0; k < NCLS; ++k) ssum += __expf(lgts[g][k] - m);
        out[(size_t)(img0 + g) * NCLS + c] = lgts[g][c] - m - __logf(ssum);
    }
}

extern "C" void kernel_launch(void* const* d_in, const int* in_sizes, int n_in,
                              void* d_out, int out_size, void* d_ws, size_t ws_size,
                              hipStream_t stream) {
    const float* x    = (const float*)d_in[0];
    const float* fc_w = (const float*)d_in[1];
    const float* fc_b = (const float*)d_in[2];
    float* out = (float*)d_out;
    const int B = in_sizes[0] / 784;       // 8192
    const int grid = (B + G - 1) / G;      // 2048
    quanv_fused<<<grid, 256, 0, stream>>>(x, fc_w, fc_b, out);
}

// Round 2
// 104.486 us; speedup vs baseline: 1.1367x; 1.1367x over previous
//
#include <hip/hip_runtime.h>

typedef float v2f __attribute__((ext_vector_type(2)));

#define G      8      // images per block (4 packed pairs)
#define NPAIR  4
#define NCLS   10
#define FEATN  3920

__global__ __launch_bounds__(256, 3)
void quanv_fused(const float* __restrict__ x,      // (B, 784)
                 const float* __restrict__ fc_w,   // (10, 3920)
                 const float* __restrict__ fc_b,   // (10,)
                 float* __restrict__ out)          // (B, 10)
{
    const int tid  = threadIdx.x;
    const int img0 = blockIdx.x * G;
    const bool active = tid < 196;
    const int t  = active ? tid : 0;         // clamp so all addresses stay in-bounds
    const int pi = t / 14;
    const int pj = t - pi * 14;
    const int offT = (2 * pi) * 28 + 2 * pj;
    const int offB = offT + 28;
    const float* base = x + (size_t)img0 * 784;

    // Per image-pair rank-1 feature factors:
    //   filter feat[m*4+j] = P2[m] * t23[j]   (m = q0*2+q1, j = q2*2+q3)
    //   sampler feat[k]    = se[k]
    v2f P2[NPAIR][4], t23[NPAIR][4], se[NPAIR][4];

    #pragma unroll
    for (int p = 0; p < NPAIR; ++p) {
        const float* iA = base + (size_t)(2 * p) * 784;
        const float* iB = base + (size_t)(2 * p + 1) * 784;
        const float2 tA = *reinterpret_cast<const float2*>(iA + offT);
        const float2 bA = *reinterpret_cast<const float2*>(iA + offB);
        const float2 tB = *reinterpret_cast<const float2*>(iB + offT);
        const float2 bB = *reinterpret_cast<const float2*>(iB + offB);

        float sA0,cA0,sA1,cA1,sA2,cA2,sA3,cA3;
        float sB0,cB0,sB1,cB1,sB2,cB2,sB3,cB3;
        __sincosf(0.5f * tA.x, &sA0, &cA0); __sincosf(0.5f * tA.y, &sA1, &cA1);
        __sincosf(0.5f * bA.x, &sA2, &cA2); __sincosf(0.5f * bA.y, &sA3, &cA3);
        __sincosf(0.5f * tB.x, &sB0, &cB0); __sincosf(0.5f * tB.y, &sB1, &cB1);
        __sincosf(0.5f * bB.x, &sB2, &cB2); __sincosf(0.5f * bB.y, &sB3, &cB3);

        const v2f c0 = {cA0, cB0}, s0 = {sA0, sB0};
        const v2f c1 = {cA1, cB1}, s1 = {sA1, sB1};

        v2f a00 = c0 * c1, a01 = c0 * s1, a10 = s0 * c1, a11 = s0 * s1;
        #pragma unroll
        for (int r = 0; r < 8; ++r) {
            const v2f b10 = a11, b11 = a10;           // CX(0,1): row1 col-swap
            const v2f n00 = c0 * a00 - s0 * b10;      // RY(p0) on q0
            const v2f n01 = c0 * a01 - s0 * b11;
            const v2f n10 = s0 * a00 + c0 * b10;
            const v2f n11 = s0 * a01 + c0 * b11;
            a00 = n00; a01 = n01; a10 = n10; a11 = n11;
        }
        P2[p][0] = a00 * a00; P2[p][1] = a01 * a01;
        P2[p][2] = a10 * a10; P2[p][3] = a11 * a11;

        const v2f t2c = {cA2 * cA2, cB2 * cB2}, t2s = {sA2 * sA2, sB2 * sB2};
        const v2f t3c = {cA3 * cA3, cB3 * cB3}, t3s = {sA3 * sA3, sB3 * sB3};
        t23[p][0] = t2c * t3c; t23[p][1] = t2c * t3s;
        t23[p][2] = t2s * t3c; t23[p][3] = t2s * t3s;

        const v2f sa = s0 * s0;        // sin^2(tl/2), tl = p0
        const v2f sb = t3s;            // sin^2(br/2), br = p3
        const v2f na = 1.0f - sa, nb = 1.0f - sb;
        se[p][0] = na * nb; se[p][1] = na * sb;
        se[p][2] = sa * nb; se[p][3] = sa * sb;
    }

    __shared__ float red[4][NPAIR][NCLS][2];
    __shared__ float lg[G][NCLS];
    const int wave = tid >> 6;
    const int lane = tid & 63;

    #pragma unroll
    for (int c = 0; c < NCLS; ++c) {
        const float* wr = fc_w + c * FEATN;
        const float4 w0 = *reinterpret_cast<const float4*>(wr + 16 * t);
        const float4 w1 = *reinterpret_cast<const float4*>(wr + 16 * t + 4);
        const float4 w2 = *reinterpret_cast<const float4*>(wr + 16 * t + 8);
        const float4 w3 = *reinterpret_cast<const float4*>(wr + 16 * t + 12);
        const float4 ws = *reinterpret_cast<const float4*>(wr + 3136 + 4 * t);

        #pragma unroll
        for (int p = 0; p < NPAIR; ++p) {
            v2f u0 = t23[p][0] * w0.x + t23[p][1] * w0.y + t23[p][2] * w0.z + t23[p][3] * w0.w;
            v2f u1 = t23[p][0] * w1.x + t23[p][1] * w1.y + t23[p][2] * w1.z + t23[p][3] * w1.w;
            v2f u2 = t23[p][0] * w2.x + t23[p][1] * w2.y + t23[p][2] * w2.z + t23[p][3] * w2.w;
            v2f u3 = t23[p][0] * w3.x + t23[p][1] * w3.y + t23[p][2] * w3.z + t23[p][3] * w3.w;
            v2f s  = P2[p][0] * u0 + P2[p][1] * u1 + P2[p][2] * u2 + P2[p][3] * u3;
            s += se[p][0] * ws.x + se[p][1] * ws.y + se[p][2] * ws.z + se[p][3] * ws.w;

            float sx = active ? s.x : 0.f;
            float sy = active ? s.y : 0.f;
            #pragma unroll
            for (int off = 32; off > 0; off >>= 1) {
                sx += __shfl_xor(sx, off, 64);
                sy += __shfl_xor(sy, off, 64);
            }
            if (lane == 0) {
                red[wave][p][c][0] = sx;
                red[wave][p][c][1] = sy;
            }
        }
    }

    __syncthreads();
    if (tid < G * NCLS) {
        const int g = tid / NCLS, c = tid - g * NCLS;
        const int p = g >> 1, h = g & 1;
        lg[g][c] = red[0][p][c][h] + red[1][p][c][h] +
                   red[2][p][c][h] + red[3][p][c][h] + fc_b[c];
    }
    __syncthreads();
    if (tid < G * NCLS) {
        const int g = tid / NCLS, c = tid - g * NCLS;
        float m = -1e30f;
        #pragma unroll
        for (int k = 0; k < NCLS; ++k) m = fmaxf(m, lg[g][k]);
        float ss = 0.f;
        #pragma unroll
        for (int k = 0; k < NCLS; ++k) ss += __expf(lg[g][k] - m);
        out[(size_t)(img0 + g) * NCLS + c] = lg[g][c] - m - __logf(ss);
    }
}

extern "C" void kernel_launch(void* const* d_in, const int* in_sizes, int n_in,
                              void* d_out, int out_size, void* d_ws, size_t ws_size,
                              hipStream_t stream) {
    const float* x    = (const float*)d_in[0];
    const float* fc_w = (const float*)d_in[1];
    const float* fc_b = (const float*)d_in[2];
    float* out = (float*)d_out;
    const int B = in_sizes[0] / 784;          // 8192
    const int grid = (B + G - 1) / G;         // 1024
    quanv_fused<<<grid, 256, 0, stream>>>(x, fc_w, fc_b, out);
}